// Round 4
// baseline (218.989 us; speedup 1.0000x reference)
//
#include <hip/hip_runtime.h>

#define FEAT 512
#define REL_DIM 64
#define N_DRUGS 2000
#define N_TARGETS 4000
#define N_ENT_ROWS (N_DRUGS + N_TARGETS)
#define N_TRI 131072
#define NBLOCKS 256
#define NTHREADS 1024
#define TOTAL_WAVES (NBLOCKS * NTHREADS / 64)   // 4096

__device__ __forceinline__ float dot4(float4 a, float4 b) {
    return a.x * b.x + a.y * b.y + a.z * b.z + a.w * b.w;
}

__device__ __forceinline__ float waveReduce(float v) {
#pragma unroll
    for (int off = 32; off; off >>= 1) v += __shfl_xor(v, off, 64);
    return v;
}

// tanh(x) = 1 - 2/(e^{2x}+1); v_rcp_f32 rel err ~1e-7, saturates correctly.
__device__ __forceinline__ float fast_tanh(float x) {
    const float e = __expf(2.0f * x);
    return 1.0f - 2.0f * __builtin_amdgcn_rcpf(e + 1.0f);
}

// Single fused kernel. grid=256 blocks (== #CUs, all co-resident -> spin barrier
// is deadlock-free), 1024 threads (16 waves) per block.
// Phase 1: one wave per entity row (rows 0..5999) + row 6000 = relation scalars.
// Barrier: device-scope release/acquire via atomic counter in ws (memset to 0
//          on-stream before launch).
// Phase 2: one triplet per thread for gtid < 131072; triplet/index gathers are
//          PREFETCHED before the barrier (independent of phase 1).
__global__ __launch_bounds__(NTHREADS) void fused_kernel(
    const float* __restrict__ d_intra, const float* __restrict__ d_inter,
    const float* __restrict__ t_intra, const float* __restrict__ t_inter,
    const float* __restrict__ rel_emb_intra, const float* __restrict__ rel_emb_inter,
    const float* __restrict__ W_intra, const float* __restrict__ b_intra,
    const float* __restrict__ W_inter, const float* __restrict__ b_inter,
    const int* __restrict__ triplets,
    const int* __restrict__ did_sub, const int* __restrict__ tid_sub,
    float2* __restrict__ preU, float2* __restrict__ preV,
    float2* __restrict__ relC, unsigned* __restrict__ ctr,
    float* __restrict__ out)
{
    const int tid   = threadIdx.x;
    const int wave  = tid >> 6;
    const int lane  = tid & 63;
    const int gwave = blockIdx.x * (NTHREADS / 64) + wave;
    const int gtid  = blockIdx.x * NTHREADS + tid;

    // ---------- Phase-2 prefetch (independent of phase 1) ----------
    int t_u = 0, t_v = 0, t_r = 0, iu = 0, iv = 0;
    const bool do_tri = gtid < N_TRI;
    if (do_tri) {
        t_u = triplets[3 * gtid + 0];
        t_v = triplets[3 * gtid + 1];
        t_r = triplets[3 * gtid + 2];
        // u_is_drug = (r%2==0); v_is_drug = ((r/2)%2==0); r in [0,8)
        const bool ud = (t_r & 1) == 0;
        const bool vd = ((t_r >> 1) & 1) == 0;
        iu = ud ? did_sub[t_u] : tid_sub[t_u] + N_DRUGS;
        iv = vd ? did_sub[t_v] : tid_sub[t_v] + N_DRUGS;
    }

    // ---------- Phase 1: entity-table + relation scalars ----------
    for (int row = gwave; row < N_ENT_ROWS + 1; row += TOTAL_WAVES) {
        if (row < N_ENT_ROWS) {
            const float* fA;  // intra features
            const float* fB;  // inter features
            if (row < N_DRUGS) {
                fA = d_intra + (size_t)row * FEAT;
                fB = d_inter + (size_t)row * FEAT;
            } else {
                const int t = row - N_DRUGS;
                fA = t_intra + (size_t)t * FEAT;
                fB = t_inter + (size_t)t * FEAT;
            }
            // 512 floats = 128 float4; lane i handles float4 #i and #(i+64).
            const float4* a4 = (const float4*)fA;
            const float4* b4 = (const float4*)fB;
            const float4* w1 = (const float4*)W_intra;  // [0,128)=Wu [128,256)=Wv
            const float4* w2 = (const float4*)W_inter;

            const float4 aA0 = a4[lane],        aA1 = a4[lane + 64];
            const float4 bB0 = b4[lane],        bB1 = b4[lane + 64];
            const float4 wu10 = w1[lane],       wu11 = w1[lane + 64];
            const float4 wv10 = w1[lane + 128], wv11 = w1[lane + 192];
            const float4 wu20 = w2[lane],       wu21 = w2[lane + 64];
            const float4 wv20 = w2[lane + 128], wv21 = w2[lane + 192];

            float s_u1 = dot4(aA0, wu10) + dot4(aA1, wu11);
            float s_v1 = dot4(aA0, wv10) + dot4(aA1, wv11);
            float s_u2 = dot4(bB0, wu20) + dot4(bB1, wu21);
            float s_v2 = dot4(bB0, wv20) + dot4(bB1, wv21);

            s_u1 = waveReduce(s_u1);
            s_v1 = waveReduce(s_v1);
            s_u2 = waveReduce(s_u2);
            s_v2 = waveReduce(s_v2);

            if (lane == 0) {
                preU[row] = make_float2(s_u1, s_u2);
                preV[row] = make_float2(s_v1, s_v2);
            }
        } else {
            // Relation scalars: REL_DIM==64 == wave width.
            const float b1 = b_intra[0];
            const float b2 = b_inter[0];
            const float wr1 = W_intra[2 * FEAT + lane];
            const float wr2 = W_inter[2 * FEAT + lane];
#pragma unroll
            for (int r = 0; r < 8; ++r) {
                float p1 = rel_emb_intra[r * REL_DIM + lane] * wr1;
                float p2 = rel_emb_inter[r * REL_DIM + lane] * wr2;
                p1 = waveReduce(p1);
                p2 = waveReduce(p2);
                if (lane == 0) relC[r] = make_float2(p1 + b1, p2 + b2);
            }
        }
    }

    // ---------- Device-scope barrier (256 co-resident blocks) ----------
    __threadfence();          // release: this thread's table writes -> device scope
    __syncthreads();          // all waves of block done + fenced
    if (tid == 0) {
        __hip_atomic_fetch_add(ctr, 1u, __ATOMIC_ACQ_REL, __HIP_MEMORY_SCOPE_AGENT);
        while (__hip_atomic_load(ctr, __ATOMIC_ACQUIRE, __HIP_MEMORY_SCOPE_AGENT)
               < (unsigned)NBLOCKS) {
            __builtin_amdgcn_s_sleep(8);
        }
    }
    __syncthreads();          // block proceeds only after counter hit NBLOCKS

    // ---------- Phase 2: gather + tanh + store ----------
    if (do_tri) {
        const float2 cu = preU[iu];
        const float2 cv = preV[iv];
        const float2 cr = relC[t_r];
        const float s1 = cu.x + cv.x + cr.x;
        const float s2 = cu.y + cv.y + cr.y;
        out[gtid] = 0.6f * fast_tanh(s1) + 0.2f * fast_tanh(s2);
    }
}

extern "C" void kernel_launch(void* const* d_in, const int* in_sizes, int n_in,
                              void* d_out, int out_size, void* d_ws, size_t ws_size,
                              hipStream_t stream) {
    const float* d_intra        = (const float*)d_in[0];
    const float* d_inter        = (const float*)d_in[1];
    const float* t_intra        = (const float*)d_in[2];
    const float* t_inter        = (const float*)d_in[3];
    const int*   did_sub        = (const int*)d_in[4];
    const int*   tid_sub        = (const int*)d_in[5];
    const int*   triplets       = (const int*)d_in[6];
    // d_in[7], d_in[8]: u_is_drug / v_is_drug — derived arithmetically from r.
    const float* rel_emb_intra  = (const float*)d_in[9];
    const float* rel_emb_inter  = (const float*)d_in[10];
    const float* W_intra        = (const float*)d_in[11];
    const float* b_intra        = (const float*)d_in[12];
    const float* W_inter        = (const float*)d_in[13];
    const float* b_inter        = (const float*)d_in[14];

    float2* ws    = (float2*)d_ws;
    float2* preU  = ws;                    // 6000 float2 (drugs 0..1999, targets 2000..5999)
    float2* preV  = ws + N_ENT_ROWS;       // 6000 float2
    float2* relC  = preV + N_ENT_ROWS;     // 8 float2
    unsigned* ctr = (unsigned*)(relC + 8); // 1 u32 barrier counter

    // ws is poisoned 0xAA before every timed launch -> zero the counter on-stream.
    hipMemsetAsync(ctr, 0, sizeof(unsigned), stream);

    fused_kernel<<<NBLOCKS, NTHREADS, 0, stream>>>(
        d_intra, d_inter, t_intra, t_inter,
        rel_emb_intra, rel_emb_inter,
        W_intra, b_intra, W_inter, b_inter,
        triplets, did_sub, tid_sub,
        preU, preV, relC, ctr, (float*)d_out);
}

// Round 5
// 101.012 us; speedup vs baseline: 2.1680x; 2.1680x over previous
//
#include <hip/hip_runtime.h>

#define FEAT 512
#define REL_DIM 64
#define N_DRUGS 2000
#define N_TARGETS 4000
#define N_ENT_ROWS (N_DRUGS + N_TARGETS)
#define N_TRI 131072

__device__ __forceinline__ float dot4(float4 a, float4 b) {
    return a.x * b.x + a.y * b.y + a.z * b.z + a.w * b.w;
}

__device__ __forceinline__ float waveReduce(float v) {
#pragma unroll
    for (int off = 32; off; off >>= 1) v += __shfl_xor(v, off, 64);
    return v;
}

// tanh(x) = 1 - 2/(e^{2x}+1); v_rcp_f32 rel err ~1e-7, saturates correctly.
__device__ __forceinline__ float fast_tanh(float x) {
    const float e = __expf(2.0f * x);
    return 1.0f - 2.0f * __builtin_amdgcn_rcpf(e + 1.0f);
}

// One wave per entity row. Rows [0,2000)=drugs, [2000,6000)=targets,
// row 6000 = the 8 relation scalars (both branches).
// Packed outputs: preU[row]=(fu.Wu_intra, fu.Wu_inter), preV[row]=(fv.Wv_intra, fv.Wv_inter),
// relC[r]=(re.Wr_intra+b_intra, re.Wr_inter+b_inter).
__global__ __launch_bounds__(256) void precompute_kernel(
    const float* __restrict__ d_intra, const float* __restrict__ d_inter,
    const float* __restrict__ t_intra, const float* __restrict__ t_inter,
    const float* __restrict__ rel_emb_intra, const float* __restrict__ rel_emb_inter,
    const float* __restrict__ W_intra, const float* __restrict__ b_intra,
    const float* __restrict__ W_inter, const float* __restrict__ b_inter,
    float2* __restrict__ preU, float2* __restrict__ preV,
    float2* __restrict__ relC)
{
    const int wave = threadIdx.x >> 6;
    const int lane = threadIdx.x & 63;
    const int row  = blockIdx.x * 4 + wave;

    if (row < N_ENT_ROWS) {
        const float* fA;  // intra features
        const float* fB;  // inter features
        if (row < N_DRUGS) {
            fA = d_intra + (size_t)row * FEAT;
            fB = d_inter + (size_t)row * FEAT;
        } else {
            const int t = row - N_DRUGS;
            fA = t_intra + (size_t)t * FEAT;
            fB = t_inter + (size_t)t * FEAT;
        }
        // 512 floats = 128 float4; lane i handles float4 #i and #(i+64).
        const float4* a4 = (const float4*)fA;
        const float4* b4 = (const float4*)fB;
        const float4* w1 = (const float4*)W_intra;  // float4s: [0,128)=Wu [128,256)=Wv
        const float4* w2 = (const float4*)W_inter;

        const float4 aA0 = a4[lane],        aA1 = a4[lane + 64];
        const float4 bB0 = b4[lane],        bB1 = b4[lane + 64];
        const float4 wu10 = w1[lane],       wu11 = w1[lane + 64];
        const float4 wv10 = w1[lane + 128], wv11 = w1[lane + 192];
        const float4 wu20 = w2[lane],       wu21 = w2[lane + 64];
        const float4 wv20 = w2[lane + 128], wv21 = w2[lane + 192];

        float s_u1 = dot4(aA0, wu10) + dot4(aA1, wu11);
        float s_v1 = dot4(aA0, wv10) + dot4(aA1, wv11);
        float s_u2 = dot4(bB0, wu20) + dot4(bB1, wu21);
        float s_v2 = dot4(bB0, wv20) + dot4(bB1, wv21);

        s_u1 = waveReduce(s_u1);
        s_v1 = waveReduce(s_v1);
        s_u2 = waveReduce(s_u2);
        s_v2 = waveReduce(s_v2);

        if (lane == 0) {
            preU[row] = make_float2(s_u1, s_u2);
            preV[row] = make_float2(s_v1, s_v2);
        }
    } else if (row == N_ENT_ROWS) {
        // Relation scalars: REL_DIM==64 == wave width, one reduce per rel.
        const float b1 = b_intra[0];
        const float b2 = b_inter[0];
        const float wr1 = W_intra[2 * FEAT + lane];
        const float wr2 = W_inter[2 * FEAT + lane];
#pragma unroll
        for (int r = 0; r < 8; ++r) {
            float p1 = rel_emb_intra[r * REL_DIM + lane] * wr1;
            float p2 = rel_emb_inter[r * REL_DIM + lane] * wr2;
            p1 = waveReduce(p1);
            p2 = waveReduce(p2);
            if (lane == 0) relC[r] = make_float2(p1 + b1, p2 + b2);
        }
    }
}

// 2 triplets per thread: 65536 threads = 256 blocks x 256.
// int2 triplet loads (aligned), branchless index select, float2-packed
// L2-resident table gathers, float2 store.
__global__ __launch_bounds__(256) void triplet_kernel(
    const int2* __restrict__ tri2,
    const int* __restrict__ did_sub, const int* __restrict__ tid_sub,
    const float2* __restrict__ preU, const float2* __restrict__ preV,
    const float2* __restrict__ relC,
    float2* __restrict__ out2)
{
    const int i = blockIdx.x * blockDim.x + threadIdx.x;  // [0, N_TRI/2)
    const int2 p0 = tri2[3 * i + 0];
    const int2 p1 = tri2[3 * i + 1];
    const int2 p2 = tri2[3 * i + 2];

    const int us[2] = {p0.x, p1.y};
    const int vs[2] = {p0.y, p2.x};
    const int rs[2] = {p1.x, p2.y};
    float res[2];

#pragma unroll
    for (int k = 0; k < 2; ++k) {
        const int u = us[k], v = vs[k], r = rs[k];
        // u_is_drug = (r%2==0); v_is_drug = ((r/2)%2==0), r in [0,8).
        const bool ud = (r & 1) == 0;
        const bool vd = ((r >> 1) & 1) == 0;
        const int du = did_sub[u], tu = tid_sub[u];
        const int dv = did_sub[v], tv = tid_sub[v];
        const int iu = ud ? du : tu + N_DRUGS;
        const int iv = vd ? dv : tv + N_DRUGS;
        const float2 cu = preU[iu];
        const float2 cv = preV[iv];
        const float2 cr = relC[r];
        const float s1 = cu.x + cv.x + cr.x;
        const float s2 = cu.y + cv.y + cr.y;
        res[k] = 0.6f * fast_tanh(s1) + 0.2f * fast_tanh(s2);
    }
    out2[i] = make_float2(res[0], res[1]);
}

extern "C" void kernel_launch(void* const* d_in, const int* in_sizes, int n_in,
                              void* d_out, int out_size, void* d_ws, size_t ws_size,
                              hipStream_t stream) {
    const float* d_intra        = (const float*)d_in[0];
    const float* d_inter        = (const float*)d_in[1];
    const float* t_intra        = (const float*)d_in[2];
    const float* t_inter        = (const float*)d_in[3];
    const int*   did_sub        = (const int*)d_in[4];
    const int*   tid_sub        = (const int*)d_in[5];
    const int*   triplets       = (const int*)d_in[6];
    // d_in[7], d_in[8]: u_is_drug / v_is_drug — derived arithmetically from r.
    const float* rel_emb_intra  = (const float*)d_in[9];
    const float* rel_emb_inter  = (const float*)d_in[10];
    const float* W_intra        = (const float*)d_in[11];
    const float* b_intra        = (const float*)d_in[12];
    const float* W_inter        = (const float*)d_in[13];
    const float* b_inter        = (const float*)d_in[14];

    float2* ws   = (float2*)d_ws;
    float2* preU = ws;                    // 6000 float2 (drugs 0..1999, targets 2000..5999)
    float2* preV = ws + N_ENT_ROWS;       // 6000 float2
    float2* relC = preV + N_ENT_ROWS;     // 8 float2

    const int rows  = N_ENT_ROWS + 1;     // +1 wave-row for relation scalars
    const int gridA = (rows + 3) / 4;     // 4 waves/block
    precompute_kernel<<<gridA, 256, 0, stream>>>(
        d_intra, d_inter, t_intra, t_inter,
        rel_emb_intra, rel_emb_inter,
        W_intra, b_intra, W_inter, b_inter,
        preU, preV, relC);

    const int gridB = (N_TRI / 2 + 255) / 256;  // 256 blocks
    triplet_kernel<<<gridB, 256, 0, stream>>>(
        (const int2*)triplets, did_sub, tid_sub, preU, preV, relC, (float2*)d_out);
}